// Round 2
// baseline (11.046 us; speedup 1.0000x reference)
//
#include <hip/hip_runtime.h>

// SimpleSpectralConv2D: 3x3 VALID conv with position-modulated weights.
// out[f,r,co,c] = relu( sum_{b,j} SMk[f,3b+j] * (Li[(r+b)*64+co+j] - Lo[r*62+co])
//                                  * x[r+b, co+j, c] )
// Shapes: x[64,64,64] f32, SMk[8,9], Li[4096], Lo[3844], out[8,62,62,64].
//
// One wave (64 threads) per block: 4 pixels x 16 channel-groups (float4).
// 9 independent dwordx4 loads issued up front; smk reads are uniform ->
// scalar s_load; stores are 16B/lane, 1KB/wave per filter plane.

#define OUTW 62
#define NPIX 3844   // 62*62
#define NF   8

__global__ __launch_bounds__(64) void spectral_conv_kernel(
    const float4* __restrict__ x4,   // [4096][16] (= [64,64,64] f32)
    const float*  __restrict__ smk,  // [72]
    const float*  __restrict__ li,   // [4096]
    const float*  __restrict__ lo,   // [3844]
    float4*       __restrict__ out4) // [8][3844][16]
{
    int tid    = threadIdx.x;
    int cg     = tid & 15;                 // channel group: c = 4*cg
    int plocal = tid >> 4;                 // 0..3
    int pix    = blockIdx.x * 4 + plocal;  // 3844 = 961*4, exact
    int r  = pix / OUTW;                   // magic-mul divide
    int co = pix - r * OUTW;

    float lov = lo[pix];

    float4 acc[NF];
    #pragma unroll
    for (int f = 0; f < NF; ++f) acc[f] = make_float4(0.f, 0.f, 0.f, 0.f);

    #pragma unroll
    for (int b = 0; b < 3; ++b) {
        #pragma unroll
        for (int j = 0; j < 3; ++j) {
            int col   = (b + r) * 64 + co + j;   // flat input pixel
            float4 xv = x4[col * 16 + cg];       // 16B coalesced
            float  t  = li[col] - lov;
            int    tap = b * 3 + j;
            #pragma unroll
            for (int f = 0; f < NF; ++f) {
                float w = smk[f * 9 + tap] * t;  // smk: uniform s_load
                acc[f].x = fmaf(w, xv.x, acc[f].x);
                acc[f].y = fmaf(w, xv.y, acc[f].y);
                acc[f].z = fmaf(w, xv.z, acc[f].z);
                acc[f].w = fmaf(w, xv.w, acc[f].w);
            }
        }
    }

    #pragma unroll
    for (int f = 0; f < NF; ++f) {
        float4 v = acc[f];
        v.x = fmaxf(v.x, 0.f);
        v.y = fmaxf(v.y, 0.f);
        v.z = fmaxf(v.z, 0.f);
        v.w = fmaxf(v.w, 0.f);
        out4[f * (NPIX * 16) + pix * 16 + cg] = v;
    }
}

extern "C" void kernel_launch(void* const* d_in, const int* in_sizes, int n_in,
                              void* d_out, int out_size, void* d_ws, size_t ws_size,
                              hipStream_t stream) {
    const float4* x4  = (const float4*)d_in[0];  // (1,64,64,64)
    const float*  smk = (const float*)d_in[1];   // (8,9)
    const float*  li  = (const float*)d_in[2];   // (1,4096)
    const float*  lo  = (const float*)d_in[3];   // (3844,1)
    float4* out4 = (float4*)d_out;               // (8,62,62,64)

    spectral_conv_kernel<<<dim3(NPIX / 4), dim3(64), 0, stream>>>(
        x4, smk, li, lo, out4);
}

// Round 3
// 10.399 us; speedup vs baseline: 1.0622x; 1.0622x over previous
//
#include <hip/hip_runtime.h>

// SimpleSpectralConv2D: 3x3 VALID conv with position-modulated weights.
// out[f,r,co,c] = relu( sum_{b,j} SMk[f,3b+j] * (Li[(r+b)*64+co+j] - Lo[r*62+co])
//                                  * x[r+b, co+j, c] )
// Shapes: x[64,64,64] f32, SMk[8,9], Li[4096], Lo[3844], out[8,62,62,64].
//
// Parallelism probe: 256-thread blocks = 4 waves; all waves share the same
// 4 pixels, each wave owns 2 filters. 3844 waves (~15/CU) with float4
// loads/stores; x-tap loads are 4x redundant across waves but L1-resident.

#define OUTW 62
#define NPIX 3844   // 62*62
#define NF   8

__global__ __launch_bounds__(256) void spectral_conv_kernel(
    const float4* __restrict__ x4,   // [4096][16] (= [64,64,64] f32)
    const float*  __restrict__ smk,  // [72]
    const float*  __restrict__ li,   // [4096]
    const float*  __restrict__ lo,   // [3844]
    float4*       __restrict__ out4) // [8][3844][16]
{
    int tid    = threadIdx.x;
    int lane   = tid & 63;
    int wid    = tid >> 6;                 // wave 0..3 -> filters 2w, 2w+1
    int cg     = lane & 15;                // channel group: c = 4*cg
    int plocal = lane >> 4;                // 0..3
    int pix    = blockIdx.x * 4 + plocal;  // 3844 = 961*4, exact
    int r  = pix / OUTW;                   // magic-mul divide
    int co = pix - r * OUTW;
    int f0 = wid * 2;

    float lov = lo[pix];

    float4 a0 = make_float4(0.f, 0.f, 0.f, 0.f);
    float4 a1 = make_float4(0.f, 0.f, 0.f, 0.f);

    #pragma unroll
    for (int b = 0; b < 3; ++b) {
        #pragma unroll
        for (int j = 0; j < 3; ++j) {
            int col   = (b + r) * 64 + co + j;   // flat input pixel
            float4 xv = x4[col * 16 + cg];       // 16B coalesced, L1-shared
            float  t  = li[col] - lov;
            int    tap = b * 3 + j;
            float  w0 = smk[f0 * 9 + tap] * t;
            float  w1 = smk[f0 * 9 + 9 + tap] * t;
            a0.x = fmaf(w0, xv.x, a0.x);
            a0.y = fmaf(w0, xv.y, a0.y);
            a0.z = fmaf(w0, xv.z, a0.z);
            a0.w = fmaf(w0, xv.w, a0.w);
            a1.x = fmaf(w1, xv.x, a1.x);
            a1.y = fmaf(w1, xv.y, a1.y);
            a1.z = fmaf(w1, xv.z, a1.z);
            a1.w = fmaf(w1, xv.w, a1.w);
        }
    }

    a0.x = fmaxf(a0.x, 0.f); a0.y = fmaxf(a0.y, 0.f);
    a0.z = fmaxf(a0.z, 0.f); a0.w = fmaxf(a0.w, 0.f);
    a1.x = fmaxf(a1.x, 0.f); a1.y = fmaxf(a1.y, 0.f);
    a1.z = fmaxf(a1.z, 0.f); a1.w = fmaxf(a1.w, 0.f);

    out4[f0 * (NPIX * 16) + pix * 16 + cg]       = a0;
    out4[(f0 + 1) * (NPIX * 16) + pix * 16 + cg] = a1;
}

extern "C" void kernel_launch(void* const* d_in, const int* in_sizes, int n_in,
                              void* d_out, int out_size, void* d_ws, size_t ws_size,
                              hipStream_t stream) {
    const float4* x4  = (const float4*)d_in[0];  // (1,64,64,64)
    const float*  smk = (const float*)d_in[1];   // (8,9)
    const float*  li  = (const float*)d_in[2];   // (1,4096)
    const float*  lo  = (const float*)d_in[3];   // (3844,1)
    float4* out4 = (float4*)d_out;               // (8,62,62,64)

    spectral_conv_kernel<<<dim3(NPIX / 4), dim3(256), 0, stream>>>(
        x4, smk, li, lo, out4);
}